// Round 5
// baseline (500.537 us; speedup 1.0000x reference)
//
#include <hip/hip_runtime.h>
#include <cmath>

// ---------------------------------------------------------------------------
// UPGAT forward — R8: dispatch-chain compression (21 -> 12 dispatches).
//
// R7 (496us) confirmed the workload is dispatch-chain-dominated (~5us per
// removed chain link). R8 removes 9 more graph nodes:
//  * N-scan: single-dispatch decoupled-lookback (was scan1/2/3); agent-scope
//    __hip_atomic ops for cross-XCD safety. NS-scan: single-block chunked.
//  * invnorm fused into afrag_es (wave covers full e0 row -> sumsq via
//    shfl_xor(16/32); writes invN[node] side-effect for build_p/score epi).
//  * ONE score GEMM for edge+slot tiles (tile-range dispatch); per-y partial
//    score slices with plain stores (no atomics, no memset); build_p sums 4.
//  * relnew GEMM folded into fused H+ENT tail GEMM (rel tiles run 16 K-steps,
//    slot tiles 32 with elu(acc*invDen) boundary at kk==15).
//  * l2norm fused into gather (ENT rows <-> out rows bijective).
// GEMM core unchanged from R6/R7 (LDS dbuf via global_load_lds, 128x128,
// 48 MFMA/K-step, split-bf16 hi/lo) — verified absmax 0.015625.
// ---------------------------------------------------------------------------

#define DDIM 512
#define MAXM 65536
#define GBM 128
#define GBN 128

typedef __attribute__((ext_vector_type(8))) short short8;
typedef __attribute__((ext_vector_type(4))) short short4v;
typedef __attribute__((ext_vector_type(4))) float fv4;
typedef unsigned short u16;
typedef unsigned long long u64;

__device__ __forceinline__ float elu1(float x) { return x > 0.f ? x : expm1f(x); }
__device__ __forceinline__ float sexp(float x) {
    float lr = x >= 0.f ? x : 0.2f * x;
    return expf(-lr);
}
// round-to-nearest-even fp32 -> bf16 bits
__device__ __forceinline__ u16 f2bf(float x) {
    unsigned u = __float_as_uint(x);
    u += 0x7FFFu + ((u >> 16) & 1u);
    return (u16)(u >> 16);
}
__device__ __forceinline__ float bf2f(u16 h) {
    return __uint_as_float((unsigned)h << 16);
}
__device__ __forceinline__ void cvt8(const float* v, short8& h8, short8& l8) {
    #pragma unroll
    for (int i = 0; i < 8; i++) {
        u16 h = f2bf(v[i]);
        h8[i] = (short)h;
        l8[i] = (short)f2bf(v[i] - bf2f(h));
    }
}
// async 16B/lane global -> LDS (dest = uniform base + lane*16, src per-lane)
__device__ __forceinline__ void gld16(const void* g, void* l) {
    __builtin_amdgcn_global_load_lds(
        (const __attribute__((address_space(1))) unsigned int*)g,
        (__attribute__((address_space(3))) unsigned int*)l,
        16, 0, 0);
}

// ---- CSR hist --------------------------------------------------------------
__global__ void hist_kernel(const int* __restrict__ src, int* __restrict__ cnt, int E)
{
    int e = blockIdx.x * 256 + threadIdx.x;
    if (e < E) atomicAdd(&cnt[src[e]], 1);
}

// ---- single-dispatch decoupled-lookback exclusive scan ---------------------
// out[0..n) exclusive, out[n] = total, optional dup to out2.
__global__ __launch_bounds__(1024)
void scan_lookback_kernel(const int* __restrict__ in, int* __restrict__ out,
                          int* __restrict__ out2, int n,
                          int* __restrict__ ticket, u64* __restrict__ state)
{
    __shared__ int sh[1024];
    __shared__ int bidSh, exSh;
    int t = threadIdx.x;
    if (t == 0) bidSh = atomicAdd(ticket, 1);
    __syncthreads();
    int bid = bidSh;
    int i = bid * 1024 + t;
    int v = (i < n) ? in[i] : 0;
    sh[t] = v;
    __syncthreads();
    for (int o = 1; o < 1024; o <<= 1) {
        int x = (t >= o) ? sh[t - o] : 0;
        __syncthreads();
        sh[t] += x;
        __syncthreads();
    }
    int incl = sh[t];
    int agg = sh[1023];
    if (t == 0) {
        u64 pub = (bid == 0) ? ((2ull << 32) | (unsigned)agg)
                             : ((1ull << 32) | (unsigned)agg);
        __hip_atomic_store(&state[bid], pub, __ATOMIC_RELEASE, __HIP_MEMORY_SCOPE_AGENT);
        int ex = 0;
        if (bid > 0) {
            int p = bid - 1;
            for (;;) {
                u64 s;
                do {
                    s = __hip_atomic_load(&state[p], __ATOMIC_ACQUIRE, __HIP_MEMORY_SCOPE_AGENT);
                } while ((s >> 32) == 0);
                ex += (int)(unsigned)s;
                if ((s >> 32) == 2ull) break;
                p--;
            }
            __hip_atomic_store(&state[bid], (2ull << 32) | (unsigned)(ex + agg),
                               __ATOMIC_RELEASE, __HIP_MEMORY_SCOPE_AGENT);
        }
        exSh = ex;
    }
    __syncthreads();
    int ex = exSh;
    if (i < n) {
        int e = ex + incl - v;
        out[i] = e;
        if (out2) out2[i] = e;
        if (i == n - 1) out[n] = ex + incl;
    }
}

// ---- single-block chunked exclusive scan (small n) -------------------------
__global__ __launch_bounds__(1024)
void scan_small_kernel(const int* __restrict__ in, int* __restrict__ out, int n)
{
    __shared__ int sh[1024];
    __shared__ int carrySh;
    int t = threadIdx.x;
    if (t == 0) carrySh = 0;
    __syncthreads();
    for (int base = 0; base < n; base += 1024) {
        int i = base + t;
        int v = (i < n) ? in[i] : 0;
        sh[t] = v;
        __syncthreads();
        for (int o = 1; o < 1024; o <<= 1) {
            int x = (t >= o) ? sh[t - o] : 0;
            __syncthreads();
            sh[t] += x;
            __syncthreads();
        }
        int carry = carrySh;
        if (i < n) out[i] = carry + sh[t] - v;
        __syncthreads();
        if (t == 1023) carrySh = carry + sh[1023];
        __syncthreads();
    }
    if (t == 0) out[n] = carrySh;
}

// ---- bucket + slotdeg fused ------------------------------------------------
__global__ void bucket_slotdeg_kernel(const int* __restrict__ src, int* __restrict__ cursor,
                                      int* __restrict__ edge_ids, int E,
                                      const int* __restrict__ triples, const int* __restrict__ rowSt,
                                      int* __restrict__ slotNode, int* __restrict__ deg, int NS)
{
    int i = blockIdx.x * 256 + threadIdx.x;
    if (i < E) { int p = atomicAdd(&cursor[src[i]], 1); edge_ids[p] = i; }
    int r = i - E;
    if (r >= 0 && r < NS) {
        int b = r >> 1, p = (r & 1) * 2;
        int n = triples[b * 3 + p];
        slotNode[r] = n;
        deg[r] = rowSt[n + 1] - rowSt[n];
    }
}

__global__ void fill_rows_kernel(const int* __restrict__ slotNode, const int* __restrict__ rowSt,
                                 const int* __restrict__ edgeIds, const int* __restrict__ slotOff,
                                 int* __restrict__ rows, int* __restrict__ srcL, int NS)
{
    int r = blockIdx.x * 256 + threadIdx.x;
    if (r >= NS) return;
    int n = slotNode[r];
    int gs = rowSt[n], d = rowSt[n + 1] - gs, mo = slotOff[r];
    for (int j = 0; j < d && mo + j < MAXM; j++) {
        rows[mo + j] = edgeIds[gs + j];
        srcL[mo + j] = n;
    }
}

// ---------------------------------------------------------------------------
// Fragment layout (split-bf16 hi/lo):
//   elem(rt,kt,lane,j) at ((rt*16+kt)*64+lane)*8+j (ushorts)
//   row = rt*16+(lane&15), k = kt*32+(lane>>4)*8+j
// ---------------------------------------------------------------------------

// ---- all weight-side fragments in ONE kernel -------------------------------
// mat 0: W1 dense; mat 1: WE transpose; mat 2: WR transpose; mat 3: relEmb dense
__global__ __launch_bounds__(256)
void wfrag_kernel(const float* __restrict__ W1, const float* __restrict__ WE,
                  const float* __restrict__ WR, const float* __restrict__ relEmb,
                  int R,
                  u16* __restrict__ W1H, u16* __restrict__ W1L,
                  u16* __restrict__ WEH, u16* __restrict__ WEL,
                  u16* __restrict__ WRH, u16* __restrict__ WRL,
                  u16* __restrict__ ArH, u16* __restrict__ ArL)
{
    int mat = blockIdx.y;
    const float* src = (mat == 0) ? W1 : (mat == 1) ? WE : (mat == 2) ? WR : relEmb;
    u16* hi = (mat == 0) ? W1H : (mat == 1) ? WEH : (mat == 2) ? WRH : ArH;
    u16* lo = (mat == 0) ? W1L : (mat == 1) ? WEL : (mat == 2) ? WRL : ArL;
    bool tr = (mat == 1 || mat == 2);
    int rows = (mat == 3) ? R : DDIM;

    int nt = ((rows + 127) >> 7) << 3;
    int wid = threadIdx.x >> 6, lane = threadIdx.x & 63;
    int l15 = lane & 15, seg = (lane >> 4) * 8;
    for (int rt = blockIdx.x * 4 + wid; rt < nt; rt += gridDim.x * 4) {
        int r = min(rt * 16 + l15, rows - 1);
        size_t base = (size_t)rt * 8192 + (size_t)lane * 8;
        #pragma unroll 2
        for (int kt = 0; kt < 16; kt++) {
            float v[8];
            if (!tr) {
                const float* p = src + (size_t)r * DDIM + seg + kt * 32;
                float4 x0 = *(const float4*)p;
                float4 x1 = *(const float4*)(p + 4);
                v[0]=x0.x; v[1]=x0.y; v[2]=x0.z; v[3]=x0.w;
                v[4]=x1.x; v[5]=x1.y; v[6]=x1.z; v[7]=x1.w;
            } else {
                int k0 = kt * 32 + seg;
                #pragma unroll
                for (int i = 0; i < 8; i++)
                    v[i] = src[(size_t)(k0 + i) * DDIM + r];
            }
            short8 h8, l8; cvt8(v, h8, l8);
            *(short8*)(hi + base + (size_t)kt * 512) = h8;
            *(short8*)(lo + base + (size_t)kt * 512) = l8;
        }
    }
}

// ---- edge + slot A-fragments + invnorm (fused) in ONE kernel ---------------
// Each lane owns one row (r = rt*16 + l15); the 4 lanes {l15+16q} cover the
// row's 512 cols -> sumsq via shfl_xor(16/32) gives invN in-kernel.
// invN[node] written as side effect (dup identical writes benign).
__global__ __launch_bounds__(256)
void afrag_es_kernel(const float* __restrict__ entEmb, float* __restrict__ invN,
                     const float* __restrict__ relEmb, const float* __restrict__ g0,
                     const int* __restrict__ rowsL, const int* __restrict__ dstIdx,
                     const int* __restrict__ relIdx, const int* __restrict__ slotNode,
                     const int* __restrict__ Mdev, int NS,
                     u16* __restrict__ AeH, u16* __restrict__ AeL,
                     u16* __restrict__ As1H, u16* __restrict__ As1L,
                     u16* __restrict__ As3H, u16* __restrict__ As3L)
{
    int M = max(1, min(MAXM, *Mdev));
    int ntE = ((M + 127) >> 7) << 3;
    int ntS = ((NS + 127) >> 7) << 3;
    int total = ntE + ntS;
    int wid = threadIdx.x >> 6, lane = threadIdx.x & 63;
    int l15 = lane & 15, seg = (lane >> 4) * 8;

    for (int g = blockIdx.x * 4 + wid; g < total; g += gridDim.x * 4) {
        bool isE = g < ntE;
        int rt = isE ? g : g - ntE;
        int node, rl = 0;
        if (isE) {
            int m = min(rt * 16 + l15, M - 1);
            int e = rowsL[m];
            node = dstIdx[e]; rl = relIdx[e];
        } else {
            node = slotNode[min(rt * 16 + l15, NS - 1)];
        }
        const float* ep = entEmb + (size_t)node * DDIM + seg;
        // pass 1: sumsq of raw row
        float ss = 0.f;
        for (int kt = 0; kt < 16; kt++) {
            float4 x0 = *(const float4*)(ep + kt * 32);
            float4 x1 = *(const float4*)(ep + kt * 32 + 4);
            ss += x0.x*x0.x + x0.y*x0.y + x0.z*x0.z + x0.w*x0.w
                + x1.x*x1.x + x1.y*x1.y + x1.z*x1.z + x1.w*x1.w;
        }
        ss += __shfl_xor(ss, 16);
        ss += __shfl_xor(ss, 32);
        float sc = 1.f / fmaxf(sqrtf(ss), 1e-12f);
        if (lane < 16) invN[node] = sc;
        size_t base = (size_t)rt * 8192 + (size_t)lane * 8;
        // pass 2 (L2-hot re-read): scale, convert, store fragments
        if (isE) {
            const float* rp = relEmb + (size_t)rl * DDIM + seg;
            #pragma unroll 4
            for (int kt = 0; kt < 16; kt++) {
                float4 x0 = *(const float4*)(ep + kt * 32);
                float4 x1 = *(const float4*)(ep + kt * 32 + 4);
                float4 y0 = *(const float4*)(rp + kt * 32);
                float4 y1 = *(const float4*)(rp + kt * 32 + 4);
                float v[8] = {sc*x0.x*y0.x, sc*x0.y*y0.y, sc*x0.z*y0.z, sc*x0.w*y0.w,
                              sc*x1.x*y1.x, sc*x1.y*y1.y, sc*x1.z*y1.z, sc*x1.w*y1.w};
                short8 h8, l8; cvt8(v, h8, l8);
                *(short8*)(AeH + base + (size_t)kt * 512) = h8;
                *(short8*)(AeL + base + (size_t)kt * 512) = l8;
            }
        } else {
            const float* gp = g0 + seg;
            #pragma unroll 2
            for (int kt = 0; kt < 16; kt++) {
                float4 x0 = *(const float4*)(ep + kt * 32);
                float4 x1 = *(const float4*)(ep + kt * 32 + 4);
                float4 y0 = *(const float4*)(gp + kt * 32);
                float4 y1 = *(const float4*)(gp + kt * 32 + 4);
                float v3[8] = {sc*x0.x, sc*x0.y, sc*x0.z, sc*x0.w,
                               sc*x1.x, sc*x1.y, sc*x1.z, sc*x1.w};
                float v1[8] = {v3[0]*y0.x, v3[1]*y0.y, v3[2]*y0.z, v3[3]*y0.w,
                               v3[4]*y1.x, v3[5]*y1.y, v3[6]*y1.z, v3[7]*y1.w};
                short8 h8, l8;
                cvt8(v3, h8, l8);
                *(short8*)(As3H + base + (size_t)kt * 512) = h8;
                *(short8*)(As3L + base + (size_t)kt * 512) = l8;
                cvt8(v1, h8, l8);
                *(short8*)(As1H + base + (size_t)kt * 512) = h8;
                *(short8*)(As1L + base + (size_t)kt * 512) = l8;
            }
        }
    }
}

// ---------------------------------------------------------------------------
// Combined score GEMM: edge tiles [0,TE) + slot tiles [TE,TE+TS).
// Per-y-block PARTIAL scores -> plain stores into scoreP[y*SCLEN + base+gm]
// (no atomics, no memset). LDS dbuf staging as R6/R7.
// ---------------------------------------------------------------------------
__global__ __launch_bounds__(256)
void gemm_score_k(const u16* __restrict__ AeH, const u16* __restrict__ AeL,
                  const u16* __restrict__ As1H, const u16* __restrict__ As1L,
                  const u16* __restrict__ W1H, const u16* __restrict__ W1L,
                  const float* __restrict__ entEmb, const float* __restrict__ invNorm,
                  const int* __restrict__ srcL, const int* __restrict__ slotNode,
                  const float* __restrict__ Wa, float* __restrict__ scoreP,
                  const int* __restrict__ Mdev, int NS, int SCLEN)
{
    __shared__ __align__(1024) u16 lds[2][32 * 512];
    int M = max(1, min(MAXM, *Mdev));
    int TE = (M + 127) >> 7, TS = (NS + 127) >> 7;
    int total = TE + TS;
    int lane = threadIdx.x & 63, wid = threadIdx.x >> 6;
    int waveM = wid >> 1, waveN = wid & 1;
    int quad = lane >> 4, l15 = lane & 15;
    int n0 = blockIdx.y * GBN;
    int ldsChunk0 = wid * 8;

    for (int tt = blockIdx.x; tt < total; tt += gridDim.x) {
        bool isE = tt < TE;
        int m0 = (isE ? tt : tt - TE) * GBM;
        int Mt = isE ? M : NS;
        const u16* g1 = isE
            ? ((wid == 0) ? AeH : (wid == 1) ? AeL : (wid == 2) ? W1H : W1L)
            : ((wid == 0) ? As1H : (wid == 1) ? As1L : (wid == 2) ? W1H : W1L);
        int rowBase = (wid < 2) ? (m0 >> 4) : (n0 >> 4);
        const u16* s1 = g1 + (size_t)rowBase * 8192 + (size_t)lane * 8;

        fv4 acc[4][4];
        #pragma unroll
        for (int i = 0; i < 4; i++)
            #pragma unroll
            for (int j = 0; j < 4; j++) acc[i][j] = fv4{0.f, 0.f, 0.f, 0.f};

        int cur = 0;
        #pragma unroll
        for (int q = 0; q < 8; q++)
            gld16(s1 + (size_t)q * 8192, &lds[0][(ldsChunk0 + q) * 512]);
        __syncthreads();

        for (int kk = 0; kk < 16; kk++) {
            if (kk < 15) {
                size_t go = (size_t)(kk + 1) * 512;
                #pragma unroll
                for (int q = 0; q < 8; q++)
                    gld16(s1 + (size_t)q * 8192 + go,
                          &lds[cur ^ 1][(ldsChunk0 + q) * 512]);
            }
            const u16* buf = &lds[cur][0];
            short8 aH[4], aL[4], bH[4], bL[4];
            #pragma unroll
            for (int i = 0; i < 4; i++) {
                aH[i] = *(const short8*)&buf[(waveM * 4 + i) * 512 + lane * 8];
                aL[i] = *(const short8*)&buf[(8 + waveM * 4 + i) * 512 + lane * 8];
                bH[i] = *(const short8*)&buf[(16 + waveN * 4 + i) * 512 + lane * 8];
                bL[i] = *(const short8*)&buf[(24 + waveN * 4 + i) * 512 + lane * 8];
            }
            #pragma unroll
            for (int i = 0; i < 4; i++)
                #pragma unroll
                for (int j = 0; j < 4; j++) {
                    acc[i][j] = __builtin_amdgcn_mfma_f32_16x16x32_bf16(aH[i], bH[j], acc[i][j], 0, 0, 0);
                    acc[i][j] = __builtin_amdgcn_mfma_f32_16x16x32_bf16(aH[i], bL[j], acc[i][j], 0, 0, 0);
                    acc[i][j] = __builtin_amdgcn_mfma_f32_16x16x32_bf16(aL[i], bH[j], acc[i][j], 0, 0, 0);
                }
            __syncthreads();
            cur ^= 1;
        }

        // score epilogue (C/D: col=lane&15, row=quad*4+reg); partial per y
        int base = isE ? 0 : MAXM;
        #pragma unroll
        for (int i = 0; i < 4; i++) {
            #pragma unroll
            for (int reg = 0; reg < 4; reg++) {
                int gm = m0 + waveM * 64 + i * 16 + quad * 4 + reg;
                bool valid = gm < Mt;
                int gmc = valid ? gm : 0;
                int srcn = isE ? srcL[gmc] : slotNode[gmc];
                float invs = invNorm[srcn];
                float s = 0.f;
                #pragma unroll
                for (int j = 0; j < 4; j++) {
                    int col = n0 + waveN * 64 + j * 16 + l15;
                    float hv = entEmb[(size_t)srcn * DDIM + col];
                    float wv = Wa[col];
                    s += tanhf(acc[i][j][reg]) * hv * wv;
                }
                s *= invs;
                s += __shfl_xor(s, 8); s += __shfl_xor(s, 4);
                s += __shfl_xor(s, 2); s += __shfl_xor(s, 1);
                if (l15 == 0 && valid)
                    scoreP[(size_t)blockIdx.y * SCLEN + base + gm] = s;
            }
        }
    }
}

// ---------------------------------------------------------------------------
// Tail GEMM: slot tiles (fused H+ENT, 32 K-steps, elu(acc*invDen) boundary)
// + rel tiles (relnew, 16 K-steps). Plain store epilogue.
// ---------------------------------------------------------------------------
__global__ __launch_bounds__(256)
void gemm_tail_k(const u16* __restrict__ ApH, const u16* __restrict__ ApL,
                 const u16* __restrict__ W1H, const u16* __restrict__ W1L,
                 const u16* __restrict__ As3H, const u16* __restrict__ As3L,
                 const u16* __restrict__ WEH, const u16* __restrict__ WEL,
                 const u16* __restrict__ ArH, const u16* __restrict__ ArL,
                 const u16* __restrict__ WRH, const u16* __restrict__ WRL,
                 const float* __restrict__ invDenom,
                 float* __restrict__ ENT, float* __restrict__ relnew, int NS, int R)
{
    __shared__ __align__(1024) u16 lds[2][32 * 512];
    int lane = threadIdx.x & 63, wid = threadIdx.x >> 6;
    int waveM = wid >> 1, waveN = wid & 1;
    int quad = lane >> 4, l15 = lane & 15;
    int n0 = blockIdx.y * GBN;
    int TS = (NS + 127) >> 7, TR = (R + 127) >> 7;
    int total = TS + TR;
    int ldsChunk0 = wid * 8;

    for (int tt = blockIdx.x; tt < total; tt += gridDim.x) {
        bool fused = tt < TS;
        int m0 = (fused ? tt : tt - TS) * GBM;
        int Mt = fused ? NS : R;
        float* Cout = fused ? ENT : relnew;
        const u16* g1 = fused
            ? ((wid == 0) ? ApH : (wid == 1) ? ApL : (wid == 2) ? W1H : W1L)
            : ((wid == 0) ? ArH : (wid == 1) ? ArL : (wid == 2) ? WRH : WRL);
        const u16* g2 = fused
            ? ((wid == 0) ? As3H : (wid == 1) ? As3L : (wid == 2) ? WEH : WEL)
            : nullptr;
        int nkk = fused ? 32 : 16;
        int rowBase = (wid < 2) ? (m0 >> 4) : (n0 >> 4);
        const u16* s1 = g1 + (size_t)rowBase * 8192 + (size_t)lane * 8;
        const u16* s2 = fused ? g2 + (size_t)rowBase * 8192 + (size_t)lane * 8 : nullptr;

        fv4 acc[4][4];
        #pragma unroll
        for (int i = 0; i < 4; i++)
            #pragma unroll
            for (int j = 0; j < 4; j++) acc[i][j] = fv4{0.f, 0.f, 0.f, 0.f};

        int cur = 0;
        #pragma unroll
        for (int q = 0; q < 8; q++)
            gld16(s1 + (size_t)q * 8192, &lds[0][(ldsChunk0 + q) * 512]);
        __syncthreads();

        for (int kk = 0; kk < nkk; kk++) {
            int kn = kk + 1;
            if (kn < nkk) {
                const u16* sp = (fused && kn >= 16) ? s2 : s1;
                size_t go = (size_t)(kn & 15) * 512;
                #pragma unroll
                for (int q = 0; q < 8; q++)
                    gld16(sp + (size_t)q * 8192 + go,
                          &lds[cur ^ 1][(ldsChunk0 + q) * 512]);
            }
            const u16* buf = &lds[cur][0];
            short8 aH[4], aL[4], bH[4], bL[4];
            #pragma unroll
            for (int i = 0; i < 4; i++) {
                aH[i] = *(const short8*)&buf[(waveM * 4 + i) * 512 + lane * 8];
                aL[i] = *(const short8*)&buf[(8 + waveM * 4 + i) * 512 + lane * 8];
                bH[i] = *(const short8*)&buf[(16 + waveN * 4 + i) * 512 + lane * 8];
                bL[i] = *(const short8*)&buf[(24 + waveN * 4 + i) * 512 + lane * 8];
            }
            #pragma unroll
            for (int i = 0; i < 4; i++)
                #pragma unroll
                for (int j = 0; j < 4; j++) {
                    acc[i][j] = __builtin_amdgcn_mfma_f32_16x16x32_bf16(aH[i], bH[j], acc[i][j], 0, 0, 0);
                    acc[i][j] = __builtin_amdgcn_mfma_f32_16x16x32_bf16(aH[i], bL[j], acc[i][j], 0, 0, 0);
                    acc[i][j] = __builtin_amdgcn_mfma_f32_16x16x32_bf16(aL[i], bH[j], acc[i][j], 0, 0, 0);
                }
            if (fused && kk == 15) {
                #pragma unroll
                for (int i = 0; i < 4; i++)
                    #pragma unroll
                    for (int reg = 0; reg < 4; reg++) {
                        int gm = m0 + waveM * 64 + i * 16 + quad * 4 + reg;
                        float idv = invDenom[min(gm, Mt - 1)];
                        #pragma unroll
                        for (int j = 0; j < 4; j++)
                            acc[i][j][reg] = elu1(acc[i][j][reg] * idv);
                    }
            }
            __syncthreads();
            cur ^= 1;
        }

        #pragma unroll
        for (int i = 0; i < 4; i++) {
            #pragma unroll
            for (int reg = 0; reg < 4; reg++) {
                int gm = m0 + waveM * 64 + i * 16 + quad * 4 + reg;
                if (gm >= Mt) continue;
                #pragma unroll
                for (int j = 0; j < 4; j++) {
                    int col = n0 + waveN * 64 + j * 16 + l15;
                    Cout[(size_t)gm * DDIM + col] = acc[i][j][reg];
                }
            }
        }
    }
}

// ---- P build: sums score slices, aggregates rows, emits split-bf16 frags --
__global__ __launch_bounds__(128)
void build_p_kernel(const float* __restrict__ entEmb, const float* __restrict__ invNorm,
                    const float* __restrict__ relEmb, const float* __restrict__ g0,
                    const int* __restrict__ slotNode, const int* __restrict__ rowSt,
                    const int* __restrict__ edgeIds, const int* __restrict__ dstIdx,
                    const int* __restrict__ relIdx, const int* __restrict__ slotOff,
                    const float* __restrict__ scoreP, int SCLEN, int NS,
                    u16* __restrict__ ApH, u16* __restrict__ ApL,
                    float* __restrict__ invDenom)
{
    int r = blockIdx.x, t = threadIdx.x;
    float4 acc = make_float4(0.f, 0.f, 0.f, 0.f);
    float dInv = 1.f;
    if (r < NS) {
        int n = slotNode[r];
        int gs = rowSt[n], d = rowSt[n + 1] - gs;
        if (d > 0) {
            int mo = slotOff[r];
            int si = MAXM + r;
            float ab = sexp(scoreP[si] + scoreP[SCLEN + si]
                          + scoreP[2 * SCLEN + si] + scoreP[3 * SCLEN + si]);
            float sc = ab * invNorm[n];
            float4 ev = *(const float4*)(entEmb + (size_t)n * DDIM + t * 4);
            float4 gv = *(const float4*)(g0 + t * 4);
            acc = make_float4(sc*ev.x*gv.x, sc*ev.y*gv.y, sc*ev.z*gv.z, sc*ev.w*gv.w);
            float denom = ab;
            for (int j = 0; j < d; j++) {
                if (mo + j >= MAXM) break;
                int e = edgeIds[gs + j];
                int ei = mo + j;
                float ae = sexp(scoreP[ei] + scoreP[SCLEN + ei]
                              + scoreP[2 * SCLEN + ei] + scoreP[3 * SCLEN + ei]);
                int dn = dstIdx[e], rl = relIdx[e];
                float s = ae * invNorm[dn];
                float4 dv = *(const float4*)(entEmb + (size_t)dn * DDIM + t * 4);
                float4 rv = *(const float4*)(relEmb + (size_t)rl * DDIM + t * 4);
                acc.x = fmaf(s, dv.x*rv.x, acc.x);
                acc.y = fmaf(s, dv.y*rv.y, acc.y);
                acc.z = fmaf(s, dv.z*rv.z, acc.z);
                acc.w = fmaf(s, dv.w*rv.w, acc.w);
                denom += ae;
            }
            dInv = 1.f / denom;
        }
    }
    // fragment write: cols 4t..4t+3 -> kt=t>>3, lane=(r&15)+16*((t>>1)&3), j0=(t&1)*4
    int kt = t >> 3;
    int lane = (r & 15) + 16 * ((t >> 1) & 3);
    int j0 = (t & 1) * 4;
    size_t fo = (size_t)(r >> 4) * 8192 + (size_t)kt * 512 + (size_t)lane * 8 + j0;
    float v[4] = {acc.x, acc.y, acc.z, acc.w};
    short4v h4, l4;
    #pragma unroll
    for (int i = 0; i < 4; i++) {
        u16 h = f2bf(v[i]);
        h4[i] = (short)h;
        l4[i] = (short)f2bf(v[i] - bf2f(h));
    }
    *(short4v*)(ApH + fo) = h4;
    *(short4v*)(ApL + fo) = l4;
    if (t == 0 && r < NS) invDenom[r] = dInv;
}

// ---- final gather [B,3,512] with fused l2norm for ENT rows -----------------
__global__ __launch_bounds__(128)
void gather_out_kernel(const int* __restrict__ triples, const float* __restrict__ ENT,
                       const float* __restrict__ relnew, float* __restrict__ out)
{
    int r = blockIdx.x;
    int b = r / 3, j = r - b * 3;
    int t = threadIdx.x;
    size_t oo = (size_t)r * DDIM + t * 4;
    if (j == 1) {
        const float* srow = relnew + (size_t)triples[r] * DDIM;
        *(float4*)(out + oo) = *(const float4*)(srow + t * 4);
        return;
    }
    const float* srow = ENT + (size_t)(b * 2 + (j == 2 ? 1 : 0)) * DDIM;
    float4 v = *(const float4*)(srow + t * 4);
    float s = v.x*v.x + v.y*v.y + v.z*v.z + v.w*v.w;
    #pragma unroll
    for (int off = 32; off > 0; off >>= 1) s += __shfl_down(s, off);
    __shared__ float ws2[2];
    if ((t & 63) == 0) ws2[t >> 6] = s;
    __syncthreads();
    float inv = 1.f / fmaxf(sqrtf(ws2[0] + ws2[1]), 1e-12f);
    *(float4*)(out + oo) = make_float4(v.x*inv, v.y*inv, v.z*inv, v.w*inv);
}

// ---------------------------------------------------------------------------
extern "C" void kernel_launch(void* const* d_in, const int* in_sizes, int n_in,
                              void* d_out, int out_size, void* d_ws, size_t ws_size,
                              hipStream_t stream)
{
    const int*   triples = (const int*)  d_in[0];
    const int*   nodes   = (const int*)  d_in[1];
    const int*   edges   = (const int*)  d_in[2];
    const float* entEmb  = (const float*)d_in[3];
    const float* relEmb  = (const float*)d_in[4];
    const float* W1      = (const float*)d_in[5];
    const float* Wa      = (const float*)d_in[6];
    const float* g0      = (const float*)d_in[7];
    const float* WE      = (const float*)d_in[8];
    const float* WR      = (const float*)d_in[9];

    const int B  = in_sizes[0] / 3;
    const int E  = in_sizes[2];
    const int N  = in_sizes[3] / DDIM;
    const int R  = in_sizes[4] / DDIM;
    const int NS = 2 * B;
    const int* srcIdx = nodes;
    const int* dstIdx = nodes + E;

    // ---- workspace carve ----
    char* ws = (char*)d_ws;
    size_t off = 0;
    auto carve = [&](size_t bytes) -> void* {
        void* p = ws + off;
        off = (off + bytes + 255) & ~(size_t)255;
        return p;
    };
    const int NS128 = ((NS + 127) / 128) * 128;
    const int R128  = ((R + 127) / 128) * 128;
    const int SCLEN = MAXM + NS128;
    float* ENT      = (float*)carve((size_t)NS * DDIM * 4);
    float* relnew   = (float*)carve((size_t)R * DDIM * 4);
    float* invNorm  = (float*)carve((size_t)N * 4);
    float* scoreP   = (float*)carve((size_t)4 * SCLEN * 4);
    float* invDen   = (float*)carve((size_t)NS * 4);
    // zero region: cnt + ticket + lookback state (single memset)
    char*  zbase    = ws + off;
    int*   cnt      = (int*)carve((size_t)N * 4);
    int*   ticket   = (int*)carve(256);
    u64*   stateN   = (u64*)carve((size_t)1024 * 8);
    size_t zbytes   = (size_t)((ws + off) - zbase);
    int*   rowSt    = (int*)carve((size_t)(N + 1) * 4);
    int*   cursor   = (int*)carve((size_t)N * 4);
    int*   edgeIds  = (int*)carve((size_t)E * 4);
    int*   slotNode = (int*)carve((size_t)NS * 4);
    int*   deg      = (int*)carve((size_t)NS * 4);
    int*   slotOff  = (int*)carve((size_t)(NS + 1) * 4);
    int*   rowsL    = (int*)carve((size_t)MAXM * 4);
    int*   srcL     = (int*)carve((size_t)MAXM * 4);
    // fragment buffers (split-bf16, MFMA fragment layout)
    u16* AeH  = (u16*)carve((size_t)MAXM * DDIM * 2);
    u16* AeL  = (u16*)carve((size_t)MAXM * DDIM * 2);
    u16* As1H = (u16*)carve((size_t)NS128 * DDIM * 2);
    u16* As1L = (u16*)carve((size_t)NS128 * DDIM * 2);
    u16* As3H = (u16*)carve((size_t)NS128 * DDIM * 2);
    u16* As3L = (u16*)carve((size_t)NS128 * DDIM * 2);
    u16* ApH  = (u16*)carve((size_t)NS128 * DDIM * 2);
    u16* ApL  = (u16*)carve((size_t)NS128 * DDIM * 2);
    u16* ArH  = (u16*)carve((size_t)R128 * DDIM * 2);
    u16* ArL  = (u16*)carve((size_t)R128 * DDIM * 2);
    u16* W1H  = (u16*)carve((size_t)DDIM * DDIM * 2);
    u16* W1L  = (u16*)carve((size_t)DDIM * DDIM * 2);
    u16* WEH  = (u16*)carve((size_t)DDIM * DDIM * 2);
    u16* WEL  = (u16*)carve((size_t)DDIM * DDIM * 2);
    u16* WRH  = (u16*)carve((size_t)DDIM * DDIM * 2);
    u16* WRL  = (u16*)carve((size_t)DDIM * DDIM * 2);
    (void)ws_size; (void)n_in; (void)out_size;

    // 1. zero (cnt + ticket + scan state) — one memset
    hipMemsetAsync(zbase, 0, zbytes, stream);
    // 2. hist
    hist_kernel<<<(E + 255) / 256, 256, 0, stream>>>(srcIdx, cnt, E);
    // 3. N-scan (lookback, 1 dispatch) -> rowSt + cursor dup
    scan_lookback_kernel<<<(N + 1023) / 1024, 1024, 0, stream>>>(
        cnt, rowSt, cursor, N, ticket, stateN);
    // 4. bucket + slotdeg
    bucket_slotdeg_kernel<<<(E + NS + 255) / 256, 256, 0, stream>>>(
        srcIdx, cursor, edgeIds, E, triples, rowSt, slotNode, deg, NS);
    // 5. NS-scan (single block) -> slotOff + Mdev
    scan_small_kernel<<<1, 1024, 0, stream>>>(deg, slotOff, NS);
    const int* Mdev = slotOff + NS;
    // 6. fill rows
    fill_rows_kernel<<<(NS + 255) / 256, 256, 0, stream>>>(slotNode, rowSt, edgeIds,
                                                           slotOff, rowsL, srcL, NS);
    // 7. weight-side fragments
    wfrag_kernel<<<dim3(8, 4), 256, 0, stream>>>(W1, WE, WR, relEmb, R,
                                                 W1H, W1L, WEH, WEL, WRH, WRL, ArH, ArL);
    // 8. edge+slot A-fragments + invnorm (fused)
    afrag_es_kernel<<<256, 256, 0, stream>>>(entEmb, invNorm, relEmb, g0,
                                             rowsL, dstIdx, edges, slotNode,
                                             Mdev, NS,
                                             AeH, AeL, As1H, As1L, As3H, As3L);
    // 9. combined score GEMM (edge+slot, partial slices, no memset/atomics)
    gemm_score_k<<<dim3(192, DDIM / GBN), 256, 0, stream>>>(
        AeH, AeL, As1H, As1L, W1H, W1L, entEmb, invNorm, srcL, slotNode,
        Wa, scoreP, Mdev, NS, SCLEN);
    // 10. P + denominators (sums slices, emits P fragments)
    build_p_kernel<<<NS128, 128, 0, stream>>>(entEmb, invNorm, relEmb, g0, slotNode,
                                              rowSt, edgeIds, dstIdx, edges, slotOff,
                                              scoreP, SCLEN, NS, ApH, ApL, invDen);
    // 11. tail GEMM: fused H+ENT (slot tiles) + relnew (rel tiles)
    int gTail = ((NS + GBM - 1) / GBM) + ((R + GBM - 1) / GBM);
    gemm_tail_k<<<dim3(gTail, DDIM / GBN), 256, 0, stream>>>(
        ApH, ApL, W1H, W1L, As3H, As3L, WEH, WEL, ArH, ArL, WRH, WRL,
        invDen, ENT, relnew, NS, R);
    // 12. gather (+l2norm fused)
    gather_out_kernel<<<B * 3, 128, 0, stream>>>(triples, ENT, relnew, (float*)d_out);
}